// Round 2
// baseline (140.484 us; speedup 1.0000x reference)
//
#include <hip/hip_runtime.h>

// CRF loss on MI355X.
// B=512, L=512, T=32, S=34. Inputs: wtv f32[512,512,32], trans f32[34,34],
// rtag i32[512,512], output_loss i32[1] (always 1). Output f32[512].
//
// Linear-domain forward algorithm: alpha_new[c] = eo[c] * sum_p alpha[p]*expT[p][c]
// with exact power-of-2 rescaling every 8 steps. One wave per batch element:
// lanes 0-31 run the forward chain (t=1..256), lanes 32-63 the backward chain
// (b_t for t=510..256), meeting at t=256: Z = sum_c af_256[c]*b_256[c].
// States 0 (START) / 33 (STOP) drop out of the linear recursion (emission NEG
// -> exactly 0 in fp32); START's t=1 contribution expT[0][c] is the acc-init.
//
// __builtin_exp2f / __builtin_log2f lower to native v_exp_f32 / v_log_f32
// (f32 exp2/log2 are legal AMDGPU ops; glibc-reserved __exp2f spelling does
// not compile under hipcc).

#define F2  1.4426950408889634f   // log2(e)
#define LN2 0.6931471805599453f

__global__ __launch_bounds__(64) void crf_kernel(
    const float* __restrict__ wtv,    // [512,512,32]
    const float* __restrict__ trans,  // [34,34]
    const int*   __restrict__ rtag,   // [512,512]
    float* __restrict__ out)          // [512]
{
    __shared__ __align__(16) float tlds[1156];  // raw translation (ln domain) for path score
    __shared__ __align__(16) float alds[64];    // [0..31] fwd alpha, [32..63] bwd g = eo*b

    const int b = blockIdx.x;
    const int l = threadIdx.x;
    const int h = l >> 5;   // 0 = forward chain, 1 = backward chain
    const int c = l & 31;   // state-1 (states 1..32)

    for (int k = l; k < 1156; k += 64) tlds[k] = trans[k];
    __syncthreads();  // once, before the main loop (graph-safe)

    // exp2-domain transition column (fwd) / row (bwd) for this lane's state
    float tc[32];
    #pragma unroll
    for (int k = 0; k < 32; ++k) {
        float tv = h ? tlds[(c + 1) * 34 + (k + 1)]   // bwd: expT[p=c+1][k+1]
                     : tlds[(k + 1) * 34 + (c + 1)];  // fwd: expT[k+1][c+1]
        tc[k] = __builtin_exp2f(F2 * tv);
    }
    float accInit = h ? 0.0f : __builtin_exp2f(F2 * tlds[c + 1]);  // expT[0][c+1], used at i==1

    const float* wb = wtv + (size_t)b * (512 * 32);
    const int*   tb = rtag + (size_t)b * 512;

    // gold-tag chunks: fwd ascending from row 0, bwd descending from row 511
    int tagf = tb[l];          // rows 0..63
    int tagb = tb[448 + l];    // rows 448..511
    int tag0 = __builtin_amdgcn_readlane(tagf, 0);
    int ptf  = tag0;           // fwd previous tag
    int pcb  = 33;             // bwd "next" tag sentinel -> first bwd add = end term trans[tag_511][33]

    // init states
    float v0    = wb[c];                                  // row 0 emission
    float st    = h ? 1.0f : __builtin_exp2f(F2 * v0);    // fwd: alpha_0 ; bwd: b_511 = 1
    float pathE = (!h && (c == tag0 - 1)) ? v0 : 0.0f;    // t=0 gold emission
    float pathT = h ? 0.0f : tlds[tag0];                  // start term trans[0][tag_0]
    int scaleE  = 0;                                      // exact log2 scale accumulator

    // emission prefetch: iteration i reads row i (fwd) / row 512-i (bwd)
    const int rowstride = h ? -32 : 32;
    float vn[8], vc[8], eo[8];
    {
        const float* p = wb + (h ? 511 * 32 : 32) + c;  // iteration 1 rows: 1 / 511
        #pragma unroll
        for (int j = 0; j < 8; ++j) vn[j] = p[j * rowstride];
    }

    for (int t0 = 1; t0 <= 249; t0 += 8) {   // 32 blocks, iterations i = 1..256
        #pragma unroll
        for (int j = 0; j < 8; ++j) { vc[j] = vn[j]; eo[j] = __builtin_exp2f(F2 * vc[j]); }
        {   // prefetch next block (rows stay in [248..264] at the tail: always in-bounds)
            int i8 = t0 + 8;
            int row8 = h ? (512 - i8) : i8;
            const float* p = wb + row8 * 32 + c;
            #pragma unroll
            for (int j = 0; j < 8; ++j) vn[j] = p[j * rowstride];
        }
        #pragma unroll
        for (int j = 0; j < 8; ++j) {
            const int i = t0 + j;
            if ((i & 63) == 0)                 tagf = tb[i + l];                    // i = 64,128,192,256
            if (((i & 63) == 1) && (i != 1))   tagb = tb[((512 - i) & ~63) + l];    // i = 65,129,193
            int ctf = __builtin_amdgcn_readlane(tagf, i & 63);          // tag_i
            int ctb = __builtin_amdgcn_readlane(tagb, (512 - i) & 63);  // tag_{512-i}

            // publish state: fwd writes alpha, bwd writes g = eo*b
            float wval = h ? st * eo[j] : st;
            alds[l] = wval;
            __builtin_amdgcn_wave_barrier();
            // broadcast read own chain's 32 values (2 distinct addrs/instr: conflict-free)
            const float4* a4 = (const float4*)(alds + (h << 5));
            float a0 = accInit, a1 = 0.0f, a2 = 0.0f, a3 = 0.0f;
            accInit = 0.0f;
            #pragma unroll
            for (int k = 0; k < 8; ++k) {
                float4 x = a4[k];
                a0 += x.x * tc[4 * k + 0];
                a1 += x.y * tc[4 * k + 1];
                a2 += x.z * tc[4 * k + 2];
                a3 += x.w * tc[4 * k + 3];
            }
            __builtin_amdgcn_wave_barrier();
            float s  = (a0 + a1) + (a2 + a3);
            float ns = h ? s : s * eo[j];

            bool doUpd = (i != 256) || (h == 0);  // i==256 is the fwd-only tail step
            st = doUpd ? ns : st;

            // gold-path score
            int myct = h ? ctb : ctf;
            if ((c == myct - 1) && doUpd) pathE += vc[j];
            int af_ = ptf * 34 + ctf;   // fwd: trans[tag_{i-1}][tag_i]
            int ab_ = ctb * 34 + pcb;   // bwd: trans[tag_u][tag_{u+1}] (u = 512-i); i==1 -> end term
            float tvv = tlds[h ? ab_ : af_];
            pathT += doUpd ? tvv : 0.0f;
            ptf = ctf;
            if (i != 256) pcb = ctb;
        }
        // exact power-of-2 rescale (per 32-lane chain group)
        float m = st;
        m = fmaxf(m, __shfl_xor(m, 1));
        m = fmaxf(m, __shfl_xor(m, 2));
        m = fmaxf(m, __shfl_xor(m, 4));
        m = fmaxf(m, __shfl_xor(m, 8));
        m = fmaxf(m, __shfl_xor(m, 16));
        int e = ((__float_as_int(m) >> 23) & 0xff) - 127;
        st *= __int_as_float((127 - e) << 23);
        scaleE += e;
    }

    // ---- epilogue: Z = sum_c af_256[c] * b_256[c] ----
    float bo   = __shfl_xor(st, 32);
    float prod = st * bo;
    prod += __shfl_xor(prod, 1);
    prod += __shfl_xor(prod, 2);
    prod += __shfl_xor(prod, 4);
    prod += __shfl_xor(prod, 8);
    prod += __shfl_xor(prod, 16);
    int scTot = scaleE + __shfl_xor(scaleE, 32);
    float total = ((float)scTot + __builtin_log2f(prod)) * LN2;

    pathE += __shfl_xor(pathE, 1);
    pathE += __shfl_xor(pathE, 2);
    pathE += __shfl_xor(pathE, 4);
    pathE += __shfl_xor(pathE, 8);
    pathE += __shfl_xor(pathE, 16);
    pathE += __shfl_xor(pathE, 32);
    // ptf = tag_256, pcb = tag_257 : the one transition neither chain covered
    float pT = pathT + __shfl_xor(pathT, 32) + tlds[ptf * 34 + pcb];

    if (l == 0) out[b] = total - (pathE + pT);
}

extern "C" void kernel_launch(void* const* d_in, const int* in_sizes, int n_in,
                              void* d_out, int out_size, void* d_ws, size_t ws_size,
                              hipStream_t stream) {
    const float* wtv   = (const float*)d_in[0];
    const float* trans = (const float*)d_in[1];
    const int*   rtag  = (const int*)d_in[2];
    (void)in_sizes; (void)n_in; (void)d_ws; (void)ws_size; (void)out_size;
    float* out = (float*)d_out;
    crf_kernel<<<512, 64, 0, stream>>>(wtv, trans, rtag, out);
}